// Round 1
// baseline (330.190 us; speedup 1.0000x reference)
//
#include <hip/hip_runtime.h>
#include <hip/hip_bf16.h>
#include <stdint.h>

typedef unsigned short u16;
typedef unsigned int u32;
typedef __attribute__((ext_vector_type(8))) short bf16x8;
typedef __attribute__((ext_vector_type(4))) float f32x4;

typedef __attribute__((address_space(3))) void lds_void;
typedef const __attribute__((address_space(1))) void gbl_void;

#define SIDE 4194304u   // 4M elems = one side's [B,H,2048,64] / [4096,1024]
#define BHSTR 131072u   // 2048*64 per (b,h)

static __device__ __forceinline__ u16 f2bf(float f) {
  union { __hip_bfloat16 b; u16 u; } cv;
  cv.b = __float2bfloat16(f);
  return cv.u;
}
static __device__ __forceinline__ float bf2f(u16 u) {
  union { __hip_bfloat16 b; u16 u; } cv;
  cv.u = u;
  return __bfloat162float(cv.b);
}

// ---------------- input convert: a,b fp32 -> bf16 row-major ----------------
__global__ __launch_bounds__(256) void k_cvt_in(const float* __restrict__ a,
                                                const float* __restrict__ b,
                                                u16* __restrict__ dst) {
  int z = blockIdx.y;
  const float* src = z ? b : a;
  size_t i = ((size_t)blockIdx.x * 256 + threadIdx.x) * 8;
  float4 x0 = *(const float4*)(src + i);
  float4 x1 = *(const float4*)(src + i + 4);
  u16 t[8] = {f2bf(x0.x), f2bf(x0.y), f2bf(x0.z), f2bf(x0.w),
              f2bf(x1.x), f2bf(x1.y), f2bf(x1.z), f2bf(x1.w)};
  *(uint4*)(dst + (size_t)z * SIDE + i) = *(uint4*)t;
}

// ---------------- bias convert (fp32 -> bf16, concat, scale z0) -----------
// scale = 1/sqrt(D) * log2(e) so scores feed exp2 directly
__global__ __launch_bounds__(256) void k_cvt_bias(
    const float* s0, const float* s1, const float* s2, const float* s3,
    const float* s4, const float* s5, u16* __restrict__ dst) {
  const float* srcs[6] = {s0, s1, s2, s3, s4, s5};
  int z = blockIdx.y;
  int i = blockIdx.x * 256 + threadIdx.x;
  float sc = (z == 0) ? 0.18033688011112042f : 1.0f;  // 0.125 * log2(e)
  dst[z * 1024 + i] = f2bf(srcs[z][i] * sc);
}

// ---------------- weight transpose fp32 -> bf16, concat, scale z0 ---------
__global__ __launch_bounds__(256) void k_transpose_w(
    const float* a0, const float* a1, const float* a2, const float* a3,
    const float* a4, const float* a5,
    u16* d0, u16* d1, u16* d2, u16* d3, u16* d4, u16* d5) {
  __shared__ u16 tile[64][72];
  const float* srcs[6] = {a0, a1, a2, a3, a4, a5};
  u16* dsts[6] = {d0, d1, d2, d3, d4, d5};
  int z = blockIdx.z;
  float sc = (z == 0) ? 0.18033688011112042f : 1.0f;  // 0.125 * log2(e)
  const float* src = srcs[z] + (size_t)(blockIdx.y * 64) * 1024 + blockIdx.x * 64;
  int t = threadIdx.x;
  int row = t >> 2, c4 = t & 3;
#pragma unroll
  for (int p = 0; p < 2; ++p) {
    int col = c4 * 8 + p * 32;
    const float* sf = src + (size_t)row * 1024 + col;
    float4 x0 = *(const float4*)sf;
    float4 x1 = *(const float4*)(sf + 4);
    u16 tmp[8] = {f2bf(x0.x * sc), f2bf(x0.y * sc), f2bf(x0.z * sc), f2bf(x0.w * sc),
                  f2bf(x1.x * sc), f2bf(x1.y * sc), f2bf(x1.z * sc), f2bf(x1.w * sc)};
    *(uint4*)(&tile[row][col]) = *(uint4*)tmp;
  }
  __syncthreads();
  u16* dst = dsts[z] + (size_t)(blockIdx.x * 64) * 1024 + blockIdx.y * 64;
#pragma unroll
  for (int p = 0; p < 2; ++p) {
    int col = c4 * 8 + p * 32;
    u16 tmp[8];
#pragma unroll
    for (int i = 0; i < 8; ++i) tmp[i] = tile[col + i][row];
    *(uint4*)(dst + (size_t)row * 1024 + col) = *(uint4*)tmp;
  }
}

// ---------------- QKV projection: [4096,1024]bf16 @ WtAB[2048,1024]^T -----
__global__ __launch_bounds__(256) void k_gemm_qkv(
    const u16* __restrict__ Aall, const u16* __restrict__ WtA,
    const u16* __restrict__ WtB, const u16* __restrict__ bias,
    u16* __restrict__ qkbuf, u16* __restrict__ vbuf) {
  __shared__ u16 Sh[8192];
  u16* As = Sh;
  u16* Bs = Sh + 4096;
  int tid = threadIdx.x;
  int wave = tid >> 6, lane = tid & 63;
  int quad = lane >> 4, lrow = lane & 15;
  int wr = wave >> 1, wc = wave & 1;
  int z = blockIdx.z;
  int m0 = blockIdx.y * 128, n0 = blockIdx.x * 128;
  const u16* A = Aall + (size_t)z * SIDE;
  const u16* Wt = z ? WtB : WtA;
  const u16* bi = bias + (size_t)z * 2048;

  f32x4 acc[4][4] = {};
  int srow = 32 * wave + (lane >> 2);
  int scol = (lane & 3) * 8;
  const u16* gA = A + (size_t)(m0 + srow) * 1024 + scol;
  const u16* gB = Wt + (size_t)(n0 + srow) * 1024 + scol;
  u16* lA = &As[(32 * wave) * 32];
  u16* lB = &Bs[(32 * wave) * 32];

  for (int k0 = 0; k0 < 1024; k0 += 32) {
    __syncthreads();
#pragma unroll
    for (int j = 0; j < 2; ++j) {
      __builtin_amdgcn_global_load_lds((gbl_void*)(gA + (size_t)(16 * j) * 1024 + k0),
                                       (lds_void*)(lA + 16 * j * 32), 16, 0, 0);
      __builtin_amdgcn_global_load_lds((gbl_void*)(gB + (size_t)(16 * j) * 1024 + k0),
                                       (lds_void*)(lB + 16 * j * 32), 16, 0, 0);
    }
    __syncthreads();
    bf16x8 af[4], bfr[4];
#pragma unroll
    for (int i = 0; i < 4; ++i)
      af[i] = *(const bf16x8*)&As[(64 * wr + 16 * i + lrow) * 32 + 8 * quad];
#pragma unroll
    for (int j = 0; j < 4; ++j)
      bfr[j] = *(const bf16x8*)&Bs[(64 * wc + 16 * j + lrow) * 32 + 8 * quad];
#pragma unroll
    for (int i = 0; i < 4; ++i)
#pragma unroll
      for (int j = 0; j < 4; ++j)
        acc[i][j] = __builtin_amdgcn_mfma_f32_16x16x32_bf16(af[i], bfr[j], acc[i][j], 0, 0, 0);
  }

  float bv[4];
#pragma unroll
  for (int j = 0; j < 4; ++j) bv[j] = bf2f(bi[n0 + 64 * wc + 16 * j + lrow]);

  int x = blockIdx.x;
  bool isv = (x >= 8);
  int h = (isv ? 2 * (x - 8) : 2 * x) + wc;
  u16* dst = (isv ? vbuf : qkbuf) + (size_t)z * SIDE;
  u16* lw = Sh + wave * 1216;  // 16 rows * stride 76 per wave

  __syncthreads();  // all waves done reading As/Bs
#pragma unroll
  for (int i = 0; i < 4; ++i) {
#pragma unroll
    for (int j = 0; j < 4; ++j)
#pragma unroll
      for (int r = 0; r < 4; ++r)
        lw[(4 * quad + r) * 76 + 16 * j + lrow] = f2bf(acc[i][j][r] + bv[j]);
    asm volatile("s_waitcnt lgkmcnt(0)" ::: "memory");
    int row = lane >> 2, cg = (lane & 3) * 16;
    int rg = m0 + 64 * wr + 16 * i + row;
    int bb = rg >> 11, rl = rg & 2047;
    u16* dr = dst + (size_t)(bb * 16 + h) * BHSTR + (size_t)rl * 64 + cg;
    uint2 w0 = *(const uint2*)&lw[row * 76 + cg];
    uint2 w1 = *(const uint2*)&lw[row * 76 + cg + 4];
    uint2 w2 = *(const uint2*)&lw[row * 76 + cg + 8];
    uint2 w3 = *(const uint2*)&lw[row * 76 + cg + 12];
    uint4 o0 = {w0.x, w0.y, w1.x, w1.y};
    uint4 o1 = {w2.x, w2.y, w3.x, w3.y};
    *(uint4*)dr = o0;
    *(uint4*)(dr + 8) = o1;
    asm volatile("s_waitcnt lgkmcnt(0)" ::: "memory");  // WAR fence before next pass
  }
}

// ---------------- V transpose per head: [sbh][2048][64] -> [sbh][64][2048] --
__global__ __launch_bounds__(256) void k_transpose_v(const u16* __restrict__ v,
                                                     u16* __restrict__ vt) {
  __shared__ u16 tile[64][72];
  int sbh = blockIdx.y;
  int n0 = blockIdx.x * 64;
  const u16* src = v + (size_t)sbh * BHSTR + (size_t)n0 * 64;
  u16* dst = vt + (size_t)sbh * BHSTR + n0;
  int t = threadIdx.x;
  int row = t >> 2, c4 = t & 3;
#pragma unroll
  for (int p = 0; p < 2; ++p) {
    int col = c4 * 8 + p * 32;
    uint4 q = *(const uint4*)(src + (size_t)row * 64 + col);
    *(uint4*)(&tile[row][col]) = q;
  }
  __syncthreads();
#pragma unroll
  for (int p = 0; p < 2; ++p) {
    int col = c4 * 8 + p * 32;
    u16 tmp[8];
#pragma unroll
    for (int i = 0; i < 8; ++i) tmp[i] = tile[col + i][row];
    *(uint4*)(dst + (size_t)row * 2048 + col) = *(uint4*)tmp;
  }
}

// ---------------- fused dual-softmax attention, both sides ----------------
// z=0: Q=aq,K=bq,V=bv -> a_ctx ; z=1: Q=bq,K=aq,V=av -> b_ctx
// 64 l-rows per wave (256-l block): halves per-unit K/V LDS reads + staging.
// Q direct to registers; exp2 (log2e pre-folded into Wa_qk); row sums via
// MFMA against all-ones B fragment (denominator lands in epilogue layout).
__global__ __launch_bounds__(256, 2) void k_attn(
    const u16* __restrict__ qk, const u16* __restrict__ vt,
    u16* __restrict__ ctx) {
  __shared__ u16 Ks[2 * 4096];
  __shared__ u16 Vs[2 * 4096];
  __shared__ u16 Ps[4 * 4096];  // per-wave P tiles [64l][64s], swizzled
  int tid = threadIdx.x;
  int wave = tid >> 6, lane = tid & 63;
  int quad = lane >> 4, lrow = lane & 15;
  int z = blockIdx.z, bh = blockIdx.x;      // x=bh: l-tiles of one (z,bh) share an XCD
  int l0 = blockIdx.y * 256;
  const u16* Qb = qk + (size_t)z * SIDE + (size_t)bh * BHSTR + (size_t)l0 * 64;
  const u16* Kb = qk + (size_t)(1 - z) * SIDE + (size_t)bh * BHSTR;
  const u16* Vtb = vt + (size_t)(1 - z) * SIDE + (size_t)bh * BHSTR;

  // Q direct to registers: wave owns rows 64*wave .. 64*wave+63
  bf16x8 qf[4][2];
#pragma unroll
  for (int rt = 0; rt < 4; ++rt) {
    int lq = 64 * wave + 16 * rt + lrow;
    qf[rt][0] = *(const bf16x8*)&Qb[(size_t)lq * 64 + 8 * quad];
    qf[rt][1] = *(const bf16x8*)&Qb[(size_t)lq * 64 + 32 + 8 * quad];
  }

  // stage K/V round 0 into buffer 0 (granule-swizzled)
#pragma unroll
  for (int p = 0; p < 2; ++p) {
    int G0 = p * 256 + wave * 64;
    int G = G0 + lane;
    int row = G >> 3, c = G & 7;
    int sw = (c ^ (row & 7)) * 8;
    __builtin_amdgcn_global_load_lds((gbl_void*)(Kb + (size_t)row * 64 + sw),
                                     (lds_void*)(Ks + G0 * 8), 16, 0, 0);
    __builtin_amdgcn_global_load_lds((gbl_void*)(Vtb + (size_t)row * 2048 + sw),
                                     (lds_void*)(Vs + G0 * 8), 16, 0, 0);
  }

  bf16x8 ones;
  {
    short o = 0x3F80;  // bf16 1.0
#pragma unroll
    for (int i = 0; i < 8; ++i) ones[i] = o;
  }

  f32x4 cacc[4][4] = {};
  f32x4 asum[4] = {};
  int e = 2 * (lrow & 7);
  u16* Pw = Ps + wave * 4096;

  for (int it = 0; it < 32; ++it) {
    __syncthreads();  // staged K/V for this round now visible
    int prty = it & 1;
    if (it + 1 < 32) {  // prefetch next round into other buffer
      int s1 = (it + 1) << 6;
      int nb = (1 - prty) * 4096;
#pragma unroll
      for (int p = 0; p < 2; ++p) {
        int G0 = p * 256 + wave * 64;
        int G = G0 + lane;
        int row = G >> 3, c = G & 7;
        int sw = (c ^ (row & 7)) * 8;
        __builtin_amdgcn_global_load_lds((gbl_void*)(Kb + (size_t)(s1 + row) * 64 + sw),
                                         (lds_void*)(Ks + nb + G0 * 8), 16, 0, 0);
        __builtin_amdgcn_global_load_lds((gbl_void*)(Vtb + (size_t)row * 2048 + s1 + sw),
                                         (lds_void*)(Vs + nb + G0 * 8), 16, 0, 0);
      }
    }
    const u16* KsC = Ks + prty * 4096;
    const u16* VsC = Vs + prty * 4096;
    // S^T = K·Q^T (scale+log2e pre-folded), exp2, packed b64 -> Pw (swizzled)
#pragma unroll
    for (int j = 0; j < 4; ++j) {
      int kr = 16 * j + lrow;
      bf16x8 kf0 = *(const bf16x8*)&KsC[(kr * 8 + (quad ^ (kr & 7))) * 8];
      bf16x8 kf1 = *(const bf16x8*)&KsC[(kr * 8 + ((quad + 4) ^ (kr & 7))) * 8];
#pragma unroll
      for (int rt = 0; rt < 4; ++rt) {
        f32x4 s = {};
        s = __builtin_amdgcn_mfma_f32_16x16x32_bf16(kf0, qf[rt][0], s, 0, 0, 0);
        s = __builtin_amdgcn_mfma_f32_16x16x32_bf16(kf1, qf[rt][1], s, 0, 0, 0);
        float e0 = exp2f(s[0]), e1 = exp2f(s[1]);
        float e2 = exp2f(s[2]), e3 = exp2f(s[3]);
        uint2 pk;
        pk.x = ((u32)f2bf(e1) << 16) | (u32)f2bf(e0);
        pk.y = ((u32)f2bf(e3) << 16) | (u32)f2bf(e2);
        *(uint2*)&Pw[(16 * rt + lrow) * 64 + ((4 * j + quad) ^ e) * 4] = pk;
      }
    }
    asm volatile("s_waitcnt lgkmcnt(0)" ::: "memory");  // wave-private Ps round-trip
    bf16x8 pf[4][2];
#pragma unroll
    for (int rt = 0; rt < 4; ++rt) {
      const u16* pr = &Pw[(16 * rt + lrow) * 64];
      pf[rt][0] = *(const bf16x8*)&pr[((2 * quad) ^ e) * 4];
      pf[rt][1] = *(const bf16x8*)&pr[((2 * quad + 8) ^ e) * 4];
    }
    // P @ V
#pragma unroll
    for (int j = 0; j < 4; ++j) {
      int vr = 16 * j + lrow;
      bf16x8 vf0 = *(const bf16x8*)&VsC[(vr * 8 + (quad ^ (vr & 7))) * 8];
      bf16x8 vf1 = *(const bf16x8*)&VsC[(vr * 8 + ((quad + 4) ^ (vr & 7))) * 8];
#pragma unroll
      for (int rt = 0; rt < 4; ++rt) {
        cacc[rt][j] = __builtin_amdgcn_mfma_f32_16x16x32_bf16(pf[rt][0], vf0, cacc[rt][j], 0, 0, 0);
        cacc[rt][j] = __builtin_amdgcn_mfma_f32_16x16x32_bf16(pf[rt][1], vf1, cacc[rt][j], 0, 0, 0);
      }
    }
    // row sums via MFMA against ones: asum[rt][r] = denom for l=16rt+4q+r
#pragma unroll
    for (int rt = 0; rt < 4; ++rt) {
      asum[rt] = __builtin_amdgcn_mfma_f32_16x16x32_bf16(pf[rt][0], ones, asum[rt], 0, 0, 0);
      asum[rt] = __builtin_amdgcn_mfma_f32_16x16x32_bf16(pf[rt][1], ones, asum[rt], 0, 0, 0);
    }
  }

  int bb = bh >> 4, h = bh & 15;
  u16* Ob = ctx + (size_t)z * SIDE + (size_t)(bb * 2048 + l0) * 1024 + h * 64;
#pragma unroll
  for (int rt = 0; rt < 4; ++rt) {
#pragma unroll
    for (int r = 0; r < 4; ++r) {
      float rinv = 1.0f / asum[rt][r];
      int l = 64 * wave + 16 * rt + 4 * quad + r;
#pragma unroll
      for (int j = 0; j < 4; ++j)
        Ob[(size_t)l * 1024 + 16 * j + lrow] = f2bf(cacc[rt][j][r] * rinv);
    }
  }
}

// ---------------- O projection: ctx[4096,1024]bf16 @ WtO^T + bias -> fp32 --
__global__ __launch_bounds__(256) void k_gemm_o(
    const u16* __restrict__ ctx, const u16* __restrict__ WtO,
    const u16* __restrict__ bias, float* __restrict__ out) {
  __shared__ u16 As[128 * 32];
  __shared__ u16 Bs[128 * 32];
  int tid = threadIdx.x;
  int wave = tid >> 6, lane = tid & 63;
  int quad = lane >> 4, lrow = lane & 15;
  int wr = wave >> 1, wc = wave & 1;
  int z = blockIdx.z;
  int m0 = blockIdx.y * 128, n0 = blockIdx.x * 128;
  const u16* A = ctx + (size_t)z * SIDE;
  const u16* Wt = WtO + (size_t)z * 1048576;
  const u16* bi = bias + (size_t)z * 1024;
  float* C = out + (size_t)z * SIDE;

  f32x4 acc[4][4] = {};
  int srow = 32 * wave + (lane >> 2);
  int scol = (lane & 3) * 8;
  const u16* gA = A + (size_t)(m0 + srow) * 1024 + scol;
  const u16* gB = Wt + (size_t)(n0 + srow) * 1024 + scol;
  u16* lA = &As[(32 * wave) * 32];
  u16* lB = &Bs[(32 * wave) * 32];

  for (int k0 = 0; k0 < 1024; k0 += 32) {
    __syncthreads();
#pragma unroll
    for (int j = 0; j < 2; ++j) {
      __builtin_amdgcn_global_load_lds((gbl_void*)(gA + (size_t)(16 * j) * 1024 + k0),
                                       (lds_void*)(lA + 16 * j * 32), 16, 0, 0);
      __builtin_amdgcn_global_load_lds((gbl_void*)(gB + (size_t)(16 * j) * 1024 + k0),
                                       (lds_void*)(lB + 16 * j * 32), 16, 0, 0);
    }
    __syncthreads();
    bf16x8 af[4], bfr[4];
#pragma unroll
    for (int i = 0; i < 4; ++i)
      af[i] = *(const bf16x8*)&As[(64 * wr + 16 * i + lrow) * 32 + 8 * quad];
#pragma unroll
    for (int j = 0; j < 4; ++j)
      bfr[j] = *(const bf16x8*)&Bs[(64 * wc + 16 * j + lrow) * 32 + 8 * quad];
#pragma unroll
    for (int i = 0; i < 4; ++i)
#pragma unroll
      for (int j = 0; j < 4; ++j)
        acc[i][j] = __builtin_amdgcn_mfma_f32_16x16x32_bf16(af[i], bfr[j], acc[i][j], 0, 0, 0);
  }

  float bv[4];
#pragma unroll
  for (int j = 0; j < 4; ++j) bv[j] = bf2f(bi[n0 + 64 * wc + 16 * j + lrow]);
#pragma unroll
  for (int i = 0; i < 4; ++i) {
    int row = m0 + 64 * wr + 16 * i + 4 * quad;
#pragma unroll
    for (int j = 0; j < 4; ++j) {
      int col = n0 + 64 * wc + 16 * j + lrow;
#pragma unroll
      for (int r = 0; r < 4; ++r)
        C[(size_t)(row + r) * 1024 + col] = acc[i][j][r] + bv[j];
    }
  }
}

extern "C" void kernel_launch(void* const* d_in, const int* in_sizes, int n_in,
                              void* d_out, int out_size, void* d_ws, size_t ws_size,
                              hipStream_t stream) {
  (void)in_sizes; (void)n_in; (void)out_size; (void)ws_size;
  const size_t M1 = 1048576u;
  u16* ws = (u16*)d_ws;
  u16* wtA   = ws;             // [2048,1024] concat(Wa_qk^T*0.125*log2e, Wa_v^T)
  u16* wtB   = ws + 2 * M1;    // [2048,1024] concat(Wb_qk^T, Wb_v^T)
  u16* wtO   = ws + 4 * M1;    // [2048,1024] concat(Wa_o^T, Wb_o^T)
  u16* biasQ = ws + 6 * M1;    // [2,2048]
  u16* biasO = ws + 6 * M1 + 4096;  // [2,1024]
  u16* ab    = ws + 7 * M1;    // [2][4096,1024] bf16 inputs (dead after QKV)
  u16* vt    = ab;             // alias: [2][bh][64][2048]
  u16* qkbuf = ws + 15 * M1;   // [2][bh][2048][64]
  u16* vbuf  = ws + 23 * M1;   // [2][bh][2048][64] (dead after transpose_v)
  u16* ctx   = vbuf;           // alias: [2][4096,1024]

  dim3 blk(256);
  k_cvt_in<<<dim3(2048, 2), blk, 0, stream>>>((const float*)d_in[0],
                                              (const float*)d_in[1], ab);
  k_cvt_bias<<<dim3(4, 6), blk, 0, stream>>>(
      (const float*)d_in[3], (const float*)d_in[5], (const float*)d_in[7],
      (const float*)d_in[9], (const float*)d_in[11], (const float*)d_in[13], biasQ);
  k_transpose_w<<<dim3(16, 16, 6), blk, 0, stream>>>(
      (const float*)d_in[2], (const float*)d_in[4], (const float*)d_in[6],
      (const float*)d_in[8], (const float*)d_in[10], (const float*)d_in[12],
      wtA, wtA + M1, wtB, wtB + M1, wtO, wtO + M1);
  k_gemm_qkv<<<dim3(16, 32, 2), blk, 0, stream>>>(ab, wtA, wtB, biasQ, qkbuf, vbuf);
  k_transpose_v<<<dim3(32, 64), blk, 0, stream>>>(vbuf, vt);
  k_attn<<<dim3(32, 8, 2), blk, 0, stream>>>(qkbuf, vt, ctx);
  k_gemm_o<<<dim3(8, 32, 2), blk, 0, stream>>>(ctx, wtO, biasO, (float*)d_out);
}

// Round 2
// 322.025 us; speedup vs baseline: 1.0254x; 1.0254x over previous
//
#include <hip/hip_runtime.h>
#include <hip/hip_bf16.h>
#include <stdint.h>

typedef unsigned short u16;
typedef unsigned int u32;
typedef __attribute__((ext_vector_type(8))) short bf16x8;
typedef __attribute__((ext_vector_type(4))) float f32x4;

typedef __attribute__((address_space(3))) void lds_void;
typedef const __attribute__((address_space(1))) void gbl_void;

#define SIDE 4194304u   // 4M elems = one side's [B,H,2048,64] / [4096,1024]
#define BHSTR 131072u   // 2048*64 per (b,h)

static __device__ __forceinline__ u16 f2bf(float f) {
  union { __hip_bfloat16 b; u16 u; } cv;
  cv.b = __float2bfloat16(f);
  return cv.u;
}
static __device__ __forceinline__ float bf2f(u16 u) {
  union { __hip_bfloat16 b; u16 u; } cv;
  cv.u = u;
  return __bfloat162float(cv.b);
}

// ---------------- input convert: a,b fp32 -> bf16 row-major ----------------
__global__ __launch_bounds__(256) void k_cvt_in(const float* __restrict__ a,
                                                const float* __restrict__ b,
                                                u16* __restrict__ dst) {
  int z = blockIdx.y;
  const float* src = z ? b : a;
  size_t i = ((size_t)blockIdx.x * 256 + threadIdx.x) * 8;
  float4 x0 = *(const float4*)(src + i);
  float4 x1 = *(const float4*)(src + i + 4);
  u16 t[8] = {f2bf(x0.x), f2bf(x0.y), f2bf(x0.z), f2bf(x0.w),
              f2bf(x1.x), f2bf(x1.y), f2bf(x1.z), f2bf(x1.w)};
  *(uint4*)(dst + (size_t)z * SIDE + i) = *(uint4*)t;
}

// ---------------- bias convert (fp32 -> bf16, concat, scale z0) -----------
// scale = 1/sqrt(D) * log2(e) so scores feed exp2 directly
__global__ __launch_bounds__(256) void k_cvt_bias(
    const float* s0, const float* s1, const float* s2, const float* s3,
    const float* s4, const float* s5, u16* __restrict__ dst) {
  const float* srcs[6] = {s0, s1, s2, s3, s4, s5};
  int z = blockIdx.y;
  int i = blockIdx.x * 256 + threadIdx.x;
  float sc = (z == 0) ? 0.18033688011112042f : 1.0f;  // 0.125 * log2(e)
  dst[z * 1024 + i] = f2bf(srcs[z][i] * sc);
}

// ---------------- weight transpose fp32 -> bf16, concat, scale z0 ---------
__global__ __launch_bounds__(256) void k_transpose_w(
    const float* a0, const float* a1, const float* a2, const float* a3,
    const float* a4, const float* a5,
    u16* d0, u16* d1, u16* d2, u16* d3, u16* d4, u16* d5) {
  __shared__ u16 tile[64][72];
  const float* srcs[6] = {a0, a1, a2, a3, a4, a5};
  u16* dsts[6] = {d0, d1, d2, d3, d4, d5};
  int z = blockIdx.z;
  float sc = (z == 0) ? 0.18033688011112042f : 1.0f;  // 0.125 * log2(e)
  const float* src = srcs[z] + (size_t)(blockIdx.y * 64) * 1024 + blockIdx.x * 64;
  int t = threadIdx.x;
  int row = t >> 2, c4 = t & 3;
#pragma unroll
  for (int p = 0; p < 2; ++p) {
    int col = c4 * 8 + p * 32;
    const float* sf = src + (size_t)row * 1024 + col;
    float4 x0 = *(const float4*)sf;
    float4 x1 = *(const float4*)(sf + 4);
    u16 tmp[8] = {f2bf(x0.x * sc), f2bf(x0.y * sc), f2bf(x0.z * sc), f2bf(x0.w * sc),
                  f2bf(x1.x * sc), f2bf(x1.y * sc), f2bf(x1.z * sc), f2bf(x1.w * sc)};
    *(uint4*)(&tile[row][col]) = *(uint4*)tmp;
  }
  __syncthreads();
  u16* dst = dsts[z] + (size_t)(blockIdx.x * 64) * 1024 + blockIdx.y * 64;
#pragma unroll
  for (int p = 0; p < 2; ++p) {
    int col = c4 * 8 + p * 32;
    u16 tmp[8];
#pragma unroll
    for (int i = 0; i < 8; ++i) tmp[i] = tile[col + i][row];
    *(uint4*)(dst + (size_t)row * 1024 + col) = *(uint4*)tmp;
  }
}

// ---------------- QKV projection: [4096,1024]bf16 @ WtAB[2048,1024]^T -----
__global__ __launch_bounds__(256) void k_gemm_qkv(
    const u16* __restrict__ Aall, const u16* __restrict__ WtA,
    const u16* __restrict__ WtB, const u16* __restrict__ bias,
    u16* __restrict__ qkbuf, u16* __restrict__ vbuf) {
  __shared__ u16 Sh[8192];
  u16* As = Sh;
  u16* Bs = Sh + 4096;
  int tid = threadIdx.x;
  int wave = tid >> 6, lane = tid & 63;
  int quad = lane >> 4, lrow = lane & 15;
  int wr = wave >> 1, wc = wave & 1;
  int z = blockIdx.z;
  int m0 = blockIdx.y * 128, n0 = blockIdx.x * 128;
  const u16* A = Aall + (size_t)z * SIDE;
  const u16* Wt = z ? WtB : WtA;
  const u16* bi = bias + (size_t)z * 2048;

  f32x4 acc[4][4] = {};
  int srow = 32 * wave + (lane >> 2);
  int scol = (lane & 3) * 8;
  const u16* gA = A + (size_t)(m0 + srow) * 1024 + scol;
  const u16* gB = Wt + (size_t)(n0 + srow) * 1024 + scol;
  u16* lA = &As[(32 * wave) * 32];
  u16* lB = &Bs[(32 * wave) * 32];

  for (int k0 = 0; k0 < 1024; k0 += 32) {
    __syncthreads();
#pragma unroll
    for (int j = 0; j < 2; ++j) {
      __builtin_amdgcn_global_load_lds((gbl_void*)(gA + (size_t)(16 * j) * 1024 + k0),
                                       (lds_void*)(lA + 16 * j * 32), 16, 0, 0);
      __builtin_amdgcn_global_load_lds((gbl_void*)(gB + (size_t)(16 * j) * 1024 + k0),
                                       (lds_void*)(lB + 16 * j * 32), 16, 0, 0);
    }
    __syncthreads();
    bf16x8 af[4], bfr[4];
#pragma unroll
    for (int i = 0; i < 4; ++i)
      af[i] = *(const bf16x8*)&As[(64 * wr + 16 * i + lrow) * 32 + 8 * quad];
#pragma unroll
    for (int j = 0; j < 4; ++j)
      bfr[j] = *(const bf16x8*)&Bs[(64 * wc + 16 * j + lrow) * 32 + 8 * quad];
#pragma unroll
    for (int i = 0; i < 4; ++i)
#pragma unroll
      for (int j = 0; j < 4; ++j)
        acc[i][j] = __builtin_amdgcn_mfma_f32_16x16x32_bf16(af[i], bfr[j], acc[i][j], 0, 0, 0);
  }

  float bv[4];
#pragma unroll
  for (int j = 0; j < 4; ++j) bv[j] = bf2f(bi[n0 + 64 * wc + 16 * j + lrow]);

  int x = blockIdx.x;
  bool isv = (x >= 8);
  int h = (isv ? 2 * (x - 8) : 2 * x) + wc;
  u16* dst = (isv ? vbuf : qkbuf) + (size_t)z * SIDE;
  u16* lw = Sh + wave * 1216;  // 16 rows * stride 76 per wave

  __syncthreads();  // all waves done reading As/Bs
#pragma unroll
  for (int i = 0; i < 4; ++i) {
#pragma unroll
    for (int j = 0; j < 4; ++j)
#pragma unroll
      for (int r = 0; r < 4; ++r)
        lw[(4 * quad + r) * 76 + 16 * j + lrow] = f2bf(acc[i][j][r] + bv[j]);
    asm volatile("s_waitcnt lgkmcnt(0)" ::: "memory");
    int row = lane >> 2, cg = (lane & 3) * 16;
    int rg = m0 + 64 * wr + 16 * i + row;
    int bb = rg >> 11, rl = rg & 2047;
    u16* dr = dst + (size_t)(bb * 16 + h) * BHSTR + (size_t)rl * 64 + cg;
    uint2 w0 = *(const uint2*)&lw[row * 76 + cg];
    uint2 w1 = *(const uint2*)&lw[row * 76 + cg + 4];
    uint2 w2 = *(const uint2*)&lw[row * 76 + cg + 8];
    uint2 w3 = *(const uint2*)&lw[row * 76 + cg + 12];
    uint4 o0 = {w0.x, w0.y, w1.x, w1.y};
    uint4 o1 = {w2.x, w2.y, w3.x, w3.y};
    *(uint4*)dr = o0;
    *(uint4*)(dr + 8) = o1;
    asm volatile("s_waitcnt lgkmcnt(0)" ::: "memory");  // WAR fence before next pass
  }
}

// ---------------- V transpose per head: [sbh][2048][64] -> [sbh][64][2048] --
__global__ __launch_bounds__(256) void k_transpose_v(const u16* __restrict__ v,
                                                     u16* __restrict__ vt) {
  __shared__ u16 tile[64][72];
  int sbh = blockIdx.y;
  int n0 = blockIdx.x * 64;
  const u16* src = v + (size_t)sbh * BHSTR + (size_t)n0 * 64;
  u16* dst = vt + (size_t)sbh * BHSTR + n0;
  int t = threadIdx.x;
  int row = t >> 2, c4 = t & 3;
#pragma unroll
  for (int p = 0; p < 2; ++p) {
    int col = c4 * 8 + p * 32;
    uint4 q = *(const uint4*)(src + (size_t)row * 64 + col);
    *(uint4*)(&tile[row][col]) = q;
  }
  __syncthreads();
#pragma unroll
  for (int p = 0; p < 2; ++p) {
    int col = c4 * 8 + p * 32;
    u16 tmp[8];
#pragma unroll
    for (int i = 0; i < 8; ++i) tmp[i] = tile[col + i][row];
    *(uint4*)(dst + (size_t)row * 2048 + col) = *(uint4*)tmp;
  }
}

// ---------------- fused dual-softmax attention, both sides ----------------
// z=0: Q=aq,K=bq,V=bv -> a_ctx ; z=1: Q=bq,K=aq,V=av -> b_ctx
// Occupancy build: KVBLK=32 rounds, LDS 24KB total (Ks 8K + Vs 8K + Ps 8K),
// 32 l/wave, Q in regs, exp2 (log2e pre-folded), MFMA row-sums.
// it-loop unrolled x2 so buffer parity (and all LDS addrs) is compile-time.
__global__ __launch_bounds__(256, 4) void k_attn(
    const u16* __restrict__ qk, const u16* __restrict__ vt,
    u16* __restrict__ ctx) {
  __shared__ u16 Ks[2 * 2048];   // [2][32 s][64 d], granule-swizzled
  __shared__ u16 Vs[2 * 2048];   // [2][64 d][32 s], granule-swizzled
  __shared__ u16 Ps[4 * 1024];   // per-wave [32 l][32 s], slot-swizzled
  int tid = threadIdx.x;
  int wave = tid >> 6, lane = tid & 63;
  int quad = lane >> 4, lrow = lane & 15;
  int z = blockIdx.z, bh = blockIdx.x;   // x=bh: l-tiles of one (z,bh) share an XCD
  int l0 = blockIdx.y * 128;
  const u16* Qb = qk + (size_t)z * SIDE + (size_t)bh * BHSTR + (size_t)l0 * 64;
  const u16* Kb = qk + (size_t)(1 - z) * SIDE + (size_t)bh * BHSTR;
  const u16* Vtb = vt + (size_t)(1 - z) * SIDE + (size_t)bh * BHSTR;

  // Q -> registers: wave owns rows 32*wave .. 32*wave+31
  bf16x8 qf[2][2];
#pragma unroll
  for (int rt = 0; rt < 2; ++rt) {
    int lq = 32 * wave + 16 * rt + lrow;
    qf[rt][0] = *(const bf16x8*)&Qb[(size_t)lq * 64 + 8 * quad];
    qf[rt][1] = *(const bf16x8*)&Qb[(size_t)lq * 64 + 32 + 8 * quad];
  }

  // staging lane constants (1 K-instr + 1 V-instr per wave per round)
  int gk = wave * 64 + lane;
  int krow = gk >> 3, kc = gk & 7;       // K: 32 rows x 8 granules
  int vrow = gk >> 2, vc = gk & 3;       // V: 64 rows x 4 granules
  const u16* kSrc = Kb + (size_t)krow * 64 + ((kc ^ (krow & 7)) * 8);
  const u16* vSrc = Vtb + (size_t)vrow * 2048 + ((vc ^ (vrow & 3)) * 8);
  u16* kDst = Ks + wave * 512;           // uniform base; HW adds lane*16B
  u16* vDst = Vs + wave * 512;

  bf16x8 ones;
  {
    short o = 0x3F80;  // bf16 1.0
#pragma unroll
    for (int i = 0; i < 8; ++i) ones[i] = o;
  }

  f32x4 cacc[2][4] = {};
  f32x4 asum[2] = {};
  int ew = 2 * (lrow & 3);               // even slot-swizzle for Ps
  u16* Pw = Ps + wave * 1024;
  // loop-invariant LDS element offsets
  int kof0 = (quad ^ (lrow & 7)) * 8;
  int kof1 = ((quad + 4) ^ (lrow & 7)) * 8;
  int vof = (quad ^ (lrow & 3)) * 8;
  int prof = ((2 * quad) ^ ew) * 4;

  // prologue: stage round 0 into buffer 0
  __builtin_amdgcn_global_load_lds((gbl_void*)kSrc, (lds_void*)kDst, 16, 0, 0);
  __builtin_amdgcn_global_load_lds((gbl_void*)vSrc, (lds_void*)vDst, 16, 0, 0);

#define ATT_BODY(BUF, IT)                                                      \
  {                                                                            \
    const u16* KsC = Ks + (BUF)*2048;                                          \
    const u16* VsC = Vs + (BUF)*2048;                                          \
    _Pragma("unroll") for (int j = 0; j < 2; ++j) {                            \
      int kr = 16 * j + lrow;                                                  \
      bf16x8 kf0 = *(const bf16x8*)&KsC[kr * 64 + kof0];                       \
      bf16x8 kf1 = *(const bf16x8*)&KsC[kr * 64 + kof1];                       \
      _Pragma("unroll") for (int rt = 0; rt < 2; ++rt) {                       \
        f32x4 s = {};                                                          \
        s = __builtin_amdgcn_mfma_f32_16x16x32_bf16(kf0, qf[rt][0], s, 0, 0, 0); \
        s = __builtin_amdgcn_mfma_f32_16x16x32_bf16(kf1, qf[rt][1], s, 0, 0, 0); \
        float e0 = exp2f(s[0]), e1 = exp2f(s[1]);                              \
        float e2 = exp2f(s[2]), e3 = exp2f(s[3]);                              \
        uint2 pk;                                                              \
        pk.x = ((u32)f2bf(e1) << 16) | (u32)f2bf(e0);                          \
        pk.y = ((u32)f2bf(e3) << 16) | (u32)f2bf(e2);                          \
        *(uint2*)&Pw[(16 * rt + lrow) * 32 + (((4 * j + quad) ^ ew) * 4)] = pk; \
      }                                                                        \
    }                                                                          \
    asm volatile("s_waitcnt lgkmcnt(0)" ::: "memory");                         \
    bf16x8 pf0 = *(const bf16x8*)&Pw[lrow * 32 + prof];                        \
    bf16x8 pf1 = *(const bf16x8*)&Pw[(16 + lrow) * 32 + prof];                 \
    _Pragma("unroll") for (int jd = 0; jd < 4; ++jd) {                         \
      int vr = 16 * jd + lrow;                                                 \
      bf16x8 vf = *(const bf16x8*)&VsC[vr * 32 + vof];                         \
      cacc[0][jd] = __builtin_amdgcn_mfma_f32_16x16x32_bf16(pf0, vf, cacc[0][jd], 0, 0, 0); \
      cacc[1][jd] = __builtin_amdgcn_mfma_f32_16x16x32_bf16(pf1, vf, cacc[1][jd], 0, 0, 0); \
    }                                                                          \
    asum[0] = __builtin_amdgcn_mfma_f32_16x16x32_bf16(pf0, ones, asum[0], 0, 0, 0); \
    asum[1] = __builtin_amdgcn_mfma_f32_16x16x32_bf16(pf1, ones, asum[1], 0, 0, 0); \
  }

  for (int it2 = 0; it2 < 32; ++it2) {
    int it = it2 * 2;
    __syncthreads();  // buf0 staged (vmcnt(0) in barrier)
    // prefetch round it+1 into buf1
    __builtin_amdgcn_global_load_lds((gbl_void*)(kSrc + (size_t)(it + 1) * 2048),
                                     (lds_void*)(kDst + 2048), 16, 0, 0);
    __builtin_amdgcn_global_load_lds((gbl_void*)(vSrc + (it + 1) * 32),
                                     (lds_void*)(vDst + 2048), 16, 0, 0);
    ATT_BODY(0, it)
    __syncthreads();  // buf1 staged
    if (it2 < 31) {
      // prefetch round it+2 into buf0
      __builtin_amdgcn_global_load_lds((gbl_void*)(kSrc + (size_t)(it + 2) * 2048),
                                       (lds_void*)kDst, 16, 0, 0);
      __builtin_amdgcn_global_load_lds((gbl_void*)(vSrc + (it + 2) * 32),
                                       (lds_void*)vDst, 16, 0, 0);
    }
    ATT_BODY(1, it + 1)
  }
#undef ATT_BODY

  int bb = bh >> 4, h = bh & 15;
  u16* Ob = ctx + (size_t)z * SIDE + (size_t)(bb * 2048 + l0) * 1024 + h * 64;
#pragma unroll
  for (int rt = 0; rt < 2; ++rt) {
#pragma unroll
    for (int r = 0; r < 4; ++r) {
      float rinv = 1.0f / asum[rt][r];
      int l = 32 * wave + 16 * rt + 4 * quad + r;
#pragma unroll
      for (int j = 0; j < 4; ++j)
        Ob[(size_t)l * 1024 + 16 * j + lrow] = f2bf(cacc[rt][j][r] * rinv);
    }
  }
}

// ---------------- O projection: ctx[4096,1024]bf16 @ WtO^T + bias -> fp32 --
__global__ __launch_bounds__(256) void k_gemm_o(
    const u16* __restrict__ ctx, const u16* __restrict__ WtO,
    const u16* __restrict__ bias, float* __restrict__ out) {
  __shared__ u16 As[128 * 32];
  __shared__ u16 Bs[128 * 32];
  int tid = threadIdx.x;
  int wave = tid >> 6, lane = tid & 63;
  int quad = lane >> 4, lrow = lane & 15;
  int wr = wave >> 1, wc = wave & 1;
  int z = blockIdx.z;
  int m0 = blockIdx.y * 128, n0 = blockIdx.x * 128;
  const u16* A = ctx + (size_t)z * SIDE;
  const u16* Wt = WtO + (size_t)z * 1048576;
  const u16* bi = bias + (size_t)z * 1024;
  float* C = out + (size_t)z * SIDE;

  f32x4 acc[4][4] = {};
  int srow = 32 * wave + (lane >> 2);
  int scol = (lane & 3) * 8;
  const u16* gA = A + (size_t)(m0 + srow) * 1024 + scol;
  const u16* gB = Wt + (size_t)(n0 + srow) * 1024 + scol;
  u16* lA = &As[(32 * wave) * 32];
  u16* lB = &Bs[(32 * wave) * 32];

  for (int k0 = 0; k0 < 1024; k0 += 32) {
    __syncthreads();
#pragma unroll
    for (int j = 0; j < 2; ++j) {
      __builtin_amdgcn_global_load_lds((gbl_void*)(gA + (size_t)(16 * j) * 1024 + k0),
                                       (lds_void*)(lA + 16 * j * 32), 16, 0, 0);
      __builtin_amdgcn_global_load_lds((gbl_void*)(gB + (size_t)(16 * j) * 1024 + k0),
                                       (lds_void*)(lB + 16 * j * 32), 16, 0, 0);
    }
    __syncthreads();
    bf16x8 af[4], bfr[4];
#pragma unroll
    for (int i = 0; i < 4; ++i)
      af[i] = *(const bf16x8*)&As[(64 * wr + 16 * i + lrow) * 32 + 8 * quad];
#pragma unroll
    for (int j = 0; j < 4; ++j)
      bfr[j] = *(const bf16x8*)&Bs[(64 * wc + 16 * j + lrow) * 32 + 8 * quad];
#pragma unroll
    for (int i = 0; i < 4; ++i)
#pragma unroll
      for (int j = 0; j < 4; ++j)
        acc[i][j] = __builtin_amdgcn_mfma_f32_16x16x32_bf16(af[i], bfr[j], acc[i][j], 0, 0, 0);
  }

  float bv[4];
#pragma unroll
  for (int j = 0; j < 4; ++j) bv[j] = bf2f(bi[n0 + 64 * wc + 16 * j + lrow]);
#pragma unroll
  for (int i = 0; i < 4; ++i) {
    int row = m0 + 64 * wr + 16 * i + 4 * quad;
#pragma unroll
    for (int j = 0; j < 4; ++j) {
      int col = n0 + 64 * wc + 16 * j + lrow;
#pragma unroll
      for (int r = 0; r < 4; ++r)
        C[(size_t)(row + r) * 1024 + col] = acc[i][j][r] + bv[j];
    }
  }
}

extern "C" void kernel_launch(void* const* d_in, const int* in_sizes, int n_in,
                              void* d_out, int out_size, void* d_ws, size_t ws_size,
                              hipStream_t stream) {
  (void)in_sizes; (void)n_in; (void)out_size; (void)ws_size;
  const size_t M1 = 1048576u;
  u16* ws = (u16*)d_ws;
  u16* wtA   = ws;             // [2048,1024] concat(Wa_qk^T*0.125*log2e, Wa_v^T)
  u16* wtB   = ws + 2 * M1;    // [2048,1024] concat(Wb_qk^T, Wb_v^T)
  u16* wtO   = ws + 4 * M1;    // [2048,1024] concat(Wa_o^T, Wb_o^T)
  u16* biasQ = ws + 6 * M1;    // [2,2048]
  u16* biasO = ws + 6 * M1 + 4096;  // [2,1024]
  u16* ab    = ws + 7 * M1;    // [2][4096,1024] bf16 inputs (dead after QKV)
  u16* vt    = ab;             // alias: [2][bh][64][2048]
  u16* qkbuf = ws + 15 * M1;   // [2][bh][2048][64]
  u16* vbuf  = ws + 23 * M1;   // [2][bh][2048][64] (dead after transpose_v)
  u16* ctx   = vbuf;           // alias: [2][4096,1024]

  dim3 blk(256);
  k_cvt_in<<<dim3(2048, 2), blk, 0, stream>>>((const float*)d_in[0],
                                              (const float*)d_in[1], ab);
  k_cvt_bias<<<dim3(4, 6), blk, 0, stream>>>(
      (const float*)d_in[3], (const float*)d_in[5], (const float*)d_in[7],
      (const float*)d_in[9], (const float*)d_in[11], (const float*)d_in[13], biasQ);
  k_transpose_w<<<dim3(16, 16, 6), blk, 0, stream>>>(
      (const float*)d_in[2], (const float*)d_in[4], (const float*)d_in[6],
      (const float*)d_in[8], (const float*)d_in[10], (const float*)d_in[12],
      wtA, wtA + M1, wtB, wtB + M1, wtO, wtO + M1);
  k_gemm_qkv<<<dim3(16, 32, 2), blk, 0, stream>>>(ab, wtA, wtB, biasQ, qkbuf, vbuf);
  k_transpose_v<<<dim3(32, 64), blk, 0, stream>>>(vbuf, vt);
  k_attn<<<dim3(32, 16, 2), blk, 0, stream>>>(qkbuf, vt, ctx);
  k_gemm_o<<<dim3(8, 32, 2), blk, 0, stream>>>(ctx, wtO, biasO, (float*)d_out);
}

// Round 3
// 319.490 us; speedup vs baseline: 1.0335x; 1.0079x over previous
//
#include <hip/hip_runtime.h>
#include <hip/hip_bf16.h>
#include <stdint.h>

typedef unsigned short u16;
typedef unsigned int u32;
typedef __attribute__((ext_vector_type(8))) short bf16x8;
typedef __attribute__((ext_vector_type(4))) float f32x4;

typedef __attribute__((address_space(3))) void lds_void;
typedef const __attribute__((address_space(1))) void gbl_void;

#define SIDE 4194304u   // 4M elems = one side's [B,H,2048,64] / [4096,1024]
#define BHSTR 131072u   // 2048*64 per (b,h)

static __device__ __forceinline__ u16 f2bf(float f) {
  union { __hip_bfloat16 b; u16 u; } cv;
  cv.b = __float2bfloat16(f);
  return cv.u;
}
static __device__ __forceinline__ float bf2f(u16 u) {
  union { __hip_bfloat16 b; u16 u; } cv;
  cv.u = u;
  return __bfloat162float(cv.b);
}

// v_permlane16_swap_b32: row1(a)<->row0(b), row3(a)<->row2(b) (16-lane rows)
static __device__ __forceinline__ void pl16swap(u32& a, u32& b) {
#if __has_builtin(__builtin_amdgcn_permlane16_swap)
  typedef __attribute__((ext_vector_type(2))) unsigned int u32x2;
  u32x2 r = __builtin_amdgcn_permlane16_swap(a, b, 0, 0);
  a = r[0];
  b = r[1];
#else
  asm volatile("v_permlane16_swap_b32 %0, %1" : "+v"(a), "+v"(b));
#endif
}

// ---------------- input convert: a,b fp32 -> bf16 row-major ----------------
__global__ __launch_bounds__(256) void k_cvt_in(const float* __restrict__ a,
                                                const float* __restrict__ b,
                                                u16* __restrict__ dst) {
  int z = blockIdx.y;
  const float* src = z ? b : a;
  size_t i = ((size_t)blockIdx.x * 256 + threadIdx.x) * 8;
  float4 x0 = *(const float4*)(src + i);
  float4 x1 = *(const float4*)(src + i + 4);
  u16 t[8] = {f2bf(x0.x), f2bf(x0.y), f2bf(x0.z), f2bf(x0.w),
              f2bf(x1.x), f2bf(x1.y), f2bf(x1.z), f2bf(x1.w)};
  *(uint4*)(dst + (size_t)z * SIDE + i) = *(uint4*)t;
}

// ---------------- bias convert (fp32 -> bf16, concat, scale z0) -----------
// scale = 1/sqrt(D) * log2(e) so scores feed exp2 directly
__global__ __launch_bounds__(256) void k_cvt_bias(
    const float* s0, const float* s1, const float* s2, const float* s3,
    const float* s4, const float* s5, u16* __restrict__ dst) {
  const float* srcs[6] = {s0, s1, s2, s3, s4, s5};
  int z = blockIdx.y;
  int i = blockIdx.x * 256 + threadIdx.x;
  float sc = (z == 0) ? 0.18033688011112042f : 1.0f;  // 0.125 * log2(e)
  dst[z * 1024 + i] = f2bf(srcs[z][i] * sc);
}

// ---------------- weight transpose fp32 -> bf16, concat, scale z0 ---------
__global__ __launch_bounds__(256) void k_transpose_w(
    const float* a0, const float* a1, const float* a2, const float* a3,
    const float* a4, const float* a5,
    u16* d0, u16* d1, u16* d2, u16* d3, u16* d4, u16* d5) {
  __shared__ u16 tile[64][72];
  const float* srcs[6] = {a0, a1, a2, a3, a4, a5};
  u16* dsts[6] = {d0, d1, d2, d3, d4, d5};
  int z = blockIdx.z;
  float sc = (z == 0) ? 0.18033688011112042f : 1.0f;  // 0.125 * log2(e)
  const float* src = srcs[z] + (size_t)(blockIdx.y * 64) * 1024 + blockIdx.x * 64;
  int t = threadIdx.x;
  int row = t >> 2, c4 = t & 3;
#pragma unroll
  for (int p = 0; p < 2; ++p) {
    int col = c4 * 8 + p * 32;
    const float* sf = src + (size_t)row * 1024 + col;
    float4 x0 = *(const float4*)sf;
    float4 x1 = *(const float4*)(sf + 4);
    u16 tmp[8] = {f2bf(x0.x * sc), f2bf(x0.y * sc), f2bf(x0.z * sc), f2bf(x0.w * sc),
                  f2bf(x1.x * sc), f2bf(x1.y * sc), f2bf(x1.z * sc), f2bf(x1.w * sc)};
    *(uint4*)(&tile[row][col]) = *(uint4*)tmp;
  }
  __syncthreads();
  u16* dst = dsts[z] + (size_t)(blockIdx.x * 64) * 1024 + blockIdx.y * 64;
#pragma unroll
  for (int p = 0; p < 2; ++p) {
    int col = c4 * 8 + p * 32;
    u16 tmp[8];
#pragma unroll
    for (int i = 0; i < 8; ++i) tmp[i] = tile[col + i][row];
    *(uint4*)(dst + (size_t)row * 1024 + col) = *(uint4*)tmp;
  }
}

// ---------------- QKV projection: [4096,1024]bf16 @ WtAB[2048,1024]^T -----
__global__ __launch_bounds__(256) void k_gemm_qkv(
    const u16* __restrict__ Aall, const u16* __restrict__ WtA,
    const u16* __restrict__ WtB, const u16* __restrict__ bias,
    u16* __restrict__ qkbuf, u16* __restrict__ vbuf) {
  __shared__ u16 Sh[8192];
  u16* As = Sh;
  u16* Bs = Sh + 4096;
  int tid = threadIdx.x;
  int wave = tid >> 6, lane = tid & 63;
  int quad = lane >> 4, lrow = lane & 15;
  int wr = wave >> 1, wc = wave & 1;
  int z = blockIdx.z;
  int m0 = blockIdx.y * 128, n0 = blockIdx.x * 128;
  const u16* A = Aall + (size_t)z * SIDE;
  const u16* Wt = z ? WtB : WtA;
  const u16* bi = bias + (size_t)z * 2048;

  f32x4 acc[4][4] = {};
  int srow = 32 * wave + (lane >> 2);
  int scol = (lane & 3) * 8;
  const u16* gA = A + (size_t)(m0 + srow) * 1024 + scol;
  const u16* gB = Wt + (size_t)(n0 + srow) * 1024 + scol;
  u16* lA = &As[(32 * wave) * 32];
  u16* lB = &Bs[(32 * wave) * 32];

  for (int k0 = 0; k0 < 1024; k0 += 32) {
    __syncthreads();
#pragma unroll
    for (int j = 0; j < 2; ++j) {
      __builtin_amdgcn_global_load_lds((gbl_void*)(gA + (size_t)(16 * j) * 1024 + k0),
                                       (lds_void*)(lA + 16 * j * 32), 16, 0, 0);
      __builtin_amdgcn_global_load_lds((gbl_void*)(gB + (size_t)(16 * j) * 1024 + k0),
                                       (lds_void*)(lB + 16 * j * 32), 16, 0, 0);
    }
    __syncthreads();
    bf16x8 af[4], bfr[4];
#pragma unroll
    for (int i = 0; i < 4; ++i)
      af[i] = *(const bf16x8*)&As[(64 * wr + 16 * i + lrow) * 32 + 8 * quad];
#pragma unroll
    for (int j = 0; j < 4; ++j)
      bfr[j] = *(const bf16x8*)&Bs[(64 * wc + 16 * j + lrow) * 32 + 8 * quad];
#pragma unroll
    for (int i = 0; i < 4; ++i)
#pragma unroll
      for (int j = 0; j < 4; ++j)
        acc[i][j] = __builtin_amdgcn_mfma_f32_16x16x32_bf16(af[i], bfr[j], acc[i][j], 0, 0, 0);
  }

  float bv[4];
#pragma unroll
  for (int j = 0; j < 4; ++j) bv[j] = bf2f(bi[n0 + 64 * wc + 16 * j + lrow]);

  int x = blockIdx.x;
  bool isv = (x >= 8);
  int h = (isv ? 2 * (x - 8) : 2 * x) + wc;
  u16* dst = (isv ? vbuf : qkbuf) + (size_t)z * SIDE;
  u16* lw = Sh + wave * 1216;  // 16 rows * stride 76 per wave

  __syncthreads();  // all waves done reading As/Bs
#pragma unroll
  for (int i = 0; i < 4; ++i) {
#pragma unroll
    for (int j = 0; j < 4; ++j)
#pragma unroll
      for (int r = 0; r < 4; ++r)
        lw[(4 * quad + r) * 76 + 16 * j + lrow] = f2bf(acc[i][j][r] + bv[j]);
    asm volatile("s_waitcnt lgkmcnt(0)" ::: "memory");
    int row = lane >> 2, cg = (lane & 3) * 16;
    int rg = m0 + 64 * wr + 16 * i + row;
    int bb = rg >> 11, rl = rg & 2047;
    u16* dr = dst + (size_t)(bb * 16 + h) * BHSTR + (size_t)rl * 64 + cg;
    uint2 w0 = *(const uint2*)&lw[row * 76 + cg];
    uint2 w1 = *(const uint2*)&lw[row * 76 + cg + 4];
    uint2 w2 = *(const uint2*)&lw[row * 76 + cg + 8];
    uint2 w3 = *(const uint2*)&lw[row * 76 + cg + 12];
    uint4 o0 = {w0.x, w0.y, w1.x, w1.y};
    uint4 o1 = {w2.x, w2.y, w3.x, w3.y};
    *(uint4*)dr = o0;
    *(uint4*)(dr + 8) = o1;
    asm volatile("s_waitcnt lgkmcnt(0)" ::: "memory");  // WAR fence before next pass
  }
}

// ---------------- V transpose per head: [sbh][2048][64] -> [sbh][64][2048] --
__global__ __launch_bounds__(256) void k_transpose_v(const u16* __restrict__ v,
                                                     u16* __restrict__ vt) {
  __shared__ u16 tile[64][72];
  int sbh = blockIdx.y;
  int n0 = blockIdx.x * 64;
  const u16* src = v + (size_t)sbh * BHSTR + (size_t)n0 * 64;
  u16* dst = vt + (size_t)sbh * BHSTR + n0;
  int t = threadIdx.x;
  int row = t >> 2, c4 = t & 3;
#pragma unroll
  for (int p = 0; p < 2; ++p) {
    int col = c4 * 8 + p * 32;
    uint4 q = *(const uint4*)(src + (size_t)row * 64 + col);
    *(uint4*)(&tile[row][col]) = q;
  }
  __syncthreads();
#pragma unroll
  for (int p = 0; p < 2; ++p) {
    int col = c4 * 8 + p * 32;
    u16 tmp[8];
#pragma unroll
    for (int i = 0; i < 8; ++i) tmp[i] = tile[col + i][row];
    *(uint4*)(dst + (size_t)row * 2048 + col) = *(uint4*)tmp;
  }
}

// ---------------- fused dual-softmax attention, both sides ----------------
// z=0: Q=aq,K=bq,V=bv -> a_ctx ; z=1: Q=bq,K=aq,V=av -> b_ctx
// KVBLK=64 rounds (proven conflict-free 128B-stride XOR layout), Q in regs,
// exp2 (log2e pre-folded), MFMA row-sums.  NEW: P stays in registers —
// v_permlane16_swap redistributes S^T quads into MFMA A-fragments whose
// k-order is a block permutation [0,2,1,3]; the V B-fragment granule is
// picked with the same permutation, so no Ps LDS round-trip exists at all.
__global__ __launch_bounds__(256, 4) void k_attn(
    const u16* __restrict__ qk, const u16* __restrict__ vt,
    u16* __restrict__ ctx) {
  __shared__ u16 Ks[2 * 4096];   // [2][64 s][64 d], granule-swizzled
  __shared__ u16 Vs[2 * 4096];   // [2][64 d][64 s], granule-swizzled
  int tid = threadIdx.x;
  int wave = tid >> 6, lane = tid & 63;
  int quad = lane >> 4, lrow = lane & 15;
  int z = blockIdx.z, bh = blockIdx.x;   // x=bh: l-tiles of one (z,bh) share an XCD
  int l0 = blockIdx.y * 128;
  const u16* Qb = qk + (size_t)z * SIDE + (size_t)bh * BHSTR + (size_t)l0 * 64;
  const u16* Kb = qk + (size_t)(1 - z) * SIDE + (size_t)bh * BHSTR;
  const u16* Vtb = vt + (size_t)(1 - z) * SIDE + (size_t)bh * BHSTR;

  // Q -> registers: wave owns rows 32*wave .. 32*wave+31
  bf16x8 qf[2][2];
#pragma unroll
  for (int rt = 0; rt < 2; ++rt) {
    int lq = 32 * wave + 16 * rt + lrow;
    qf[rt][0] = *(const bf16x8*)&Qb[(size_t)lq * 64 + 8 * quad];
    qf[rt][1] = *(const bf16x8*)&Qb[(size_t)lq * 64 + 32 + 8 * quad];
  }

  // staging lane constants: 512 granules per tile, 2 per thread (p=0,1)
  int r0 = tid >> 3, c0 = tid & 7;
  int r1 = (256 + tid) >> 3;             // c1 == c0
  const u16* kS0 = Kb + (size_t)r0 * 64 + ((c0 ^ (r0 & 7)) * 8);
  const u16* kS1 = Kb + (size_t)r1 * 64 + ((c0 ^ (r1 & 7)) * 8);
  const u16* vS0 = Vtb + (size_t)r0 * 2048 + ((c0 ^ (r0 & 7)) * 8);
  const u16* vS1 = Vtb + (size_t)r1 * 2048 + ((c0 ^ (r1 & 7)) * 8);
  u16* kD0 = Ks + (wave * 64) * 8;       // uniform base; HW adds lane*16B
  u16* kD1 = Ks + (256 + wave * 64) * 8;
  u16* vD0 = Vs + (wave * 64) * 8;
  u16* vD1 = Vs + (256 + wave * 64) * 8;

  bf16x8 ones;
  {
    short o = 0x3F80;  // bf16 1.0
#pragma unroll
    for (int i = 0; i < 8; ++i) ones[i] = o;
  }

  f32x4 cacc[2][4] = {};
  f32x4 asum[2] = {};
  int gsq = 2 * (quad & 1) + (quad >> 1);  // V granule permutation [0,2,1,3]

#define STAGE(BUFOFF, IT)                                                        \
  __builtin_amdgcn_global_load_lds((gbl_void*)(kS0 + (size_t)(IT)*4096),         \
                                   (lds_void*)(kD0 + (BUFOFF)), 16, 0, 0);       \
  __builtin_amdgcn_global_load_lds((gbl_void*)(kS1 + (size_t)(IT)*4096),         \
                                   (lds_void*)(kD1 + (BUFOFF)), 16, 0, 0);       \
  __builtin_amdgcn_global_load_lds((gbl_void*)(vS0 + (size_t)(IT)*64),           \
                                   (lds_void*)(vD0 + (BUFOFF)), 16, 0, 0);       \
  __builtin_amdgcn_global_load_lds((gbl_void*)(vS1 + (size_t)(IT)*64),           \
                                   (lds_void*)(vD1 + (BUFOFF)), 16, 0, 0);

#define ATT_BODY(BUFOFF)                                                         \
  {                                                                              \
    const u16* KsC = Ks + (BUFOFF);                                              \
    const u16* VsC = Vs + (BUFOFF);                                              \
    u32 X[2][4], Y[2][4];                                                        \
    _Pragma("unroll") for (int j = 0; j < 4; ++j) {                              \
      int kr = 16 * j + lrow;                                                    \
      bf16x8 kf0 = *(const bf16x8*)&KsC[(kr * 8 + (quad ^ (kr & 7))) * 8];       \
      bf16x8 kf1 = *(const bf16x8*)&KsC[(kr * 8 + ((quad + 4) ^ (kr & 7))) * 8]; \
      _Pragma("unroll") for (int rt = 0; rt < 2; ++rt) {                         \
        f32x4 s = {};                                                            \
        s = __builtin_amdgcn_mfma_f32_16x16x32_bf16(kf0, qf[rt][0], s, 0, 0, 0); \
        s = __builtin_amdgcn_mfma_f32_16x16x32_bf16(kf1, qf[rt][1], s, 0, 0, 0); \
        float e0 = exp2f(s[0]), e1 = exp2f(s[1]);                                \
        float e2 = exp2f(s[2]), e3 = exp2f(s[3]);                                \
        X[rt][j] = ((u32)f2bf(e1) << 16) | (u32)f2bf(e0);                        \
        Y[rt][j] = ((u32)f2bf(e3) << 16) | (u32)f2bf(e2);                        \
      }                                                                          \
    }                                                                            \
    bf16x8 pf[2][2];                                                             \
    _Pragma("unroll") for (int rt = 0; rt < 2; ++rt) {                           \
      pl16swap(X[rt][0], X[rt][1]);                                              \
      pl16swap(Y[rt][0], Y[rt][1]);                                              \
      pl16swap(X[rt][2], X[rt][3]);                                              \
      pl16swap(Y[rt][2], Y[rt][3]);                                              \
      union { u32 d[4]; bf16x8 v; } u0, u1;                                      \
      u0.d[0] = X[rt][0]; u0.d[1] = Y[rt][0];                                    \
      u0.d[2] = X[rt][1]; u0.d[3] = Y[rt][1];                                    \
      u1.d[0] = X[rt][2]; u1.d[1] = Y[rt][2];                                    \
      u1.d[2] = X[rt][3]; u1.d[3] = Y[rt][3];                                    \
      pf[rt][0] = u0.v;                                                          \
      pf[rt][1] = u1.v;                                                          \
    }                                                                            \
    _Pragma("unroll") for (int jd = 0; jd < 4; ++jd) {                           \
      int vr = 16 * jd + lrow;                                                   \
      bf16x8 vf0 = *(const bf16x8*)&VsC[(vr * 8 + (gsq ^ (vr & 7))) * 8];        \
      bf16x8 vf1 = *(const bf16x8*)&VsC[(vr * 8 + ((gsq | 4) ^ (vr & 7))) * 8];  \
      _Pragma("unroll") for (int rt = 0; rt < 2; ++rt) {                         \
        cacc[rt][jd] = __builtin_amdgcn_mfma_f32_16x16x32_bf16(pf[rt][0], vf0, cacc[rt][jd], 0, 0, 0); \
        cacc[rt][jd] = __builtin_amdgcn_mfma_f32_16x16x32_bf16(pf[rt][1], vf1, cacc[rt][jd], 0, 0, 0); \
      }                                                                          \
    }                                                                            \
    _Pragma("unroll") for (int rt = 0; rt < 2; ++rt) {                           \
      asum[rt] = __builtin_amdgcn_mfma_f32_16x16x32_bf16(pf[rt][0], ones, asum[rt], 0, 0, 0); \
      asum[rt] = __builtin_amdgcn_mfma_f32_16x16x32_bf16(pf[rt][1], ones, asum[rt], 0, 0, 0); \
    }                                                                            \
  }

  // prologue: stage round 0 into buffer 0
  STAGE(0, 0)

  for (int it2 = 0; it2 < 16; ++it2) {
    int it = 2 * it2;
    __syncthreads();          // buf0 staged (barrier drains vmcnt)
    STAGE(4096, it + 1)       // prefetch next round into buf1
    ATT_BODY(0)
    __syncthreads();          // buf1 staged
    if (it2 < 15) {
      STAGE(0, it + 2)        // prefetch round it+2 into buf0
    }
    ATT_BODY(4096)
  }
#undef ATT_BODY
#undef STAGE

  int bb = bh >> 4, h = bh & 15;
  u16* Ob = ctx + (size_t)z * SIDE + (size_t)(bb * 2048 + l0) * 1024 + h * 64;
#pragma unroll
  for (int rt = 0; rt < 2; ++rt) {
#pragma unroll
    for (int r = 0; r < 4; ++r) {
      float rinv = 1.0f / asum[rt][r];
      int l = 32 * wave + 16 * rt + 4 * quad + r;
#pragma unroll
      for (int j = 0; j < 4; ++j)
        Ob[(size_t)l * 1024 + 16 * j + lrow] = f2bf(cacc[rt][j][r] * rinv);
    }
  }
}

// ---------------- O projection: ctx[4096,1024]bf16 @ WtO^T + bias -> fp32 --
__global__ __launch_bounds__(256) void k_gemm_o(
    const u16* __restrict__ ctx, const u16* __restrict__ WtO,
    const u16* __restrict__ bias, float* __restrict__ out) {
  __shared__ u16 As[128 * 32];
  __shared__ u16 Bs[128 * 32];
  int tid = threadIdx.x;
  int wave = tid >> 6, lane = tid & 63;
  int quad = lane >> 4, lrow = lane & 15;
  int wr = wave >> 1, wc = wave & 1;
  int z = blockIdx.z;
  int m0 = blockIdx.y * 128, n0 = blockIdx.x * 128;
  const u16* A = ctx + (size_t)z * SIDE;
  const u16* Wt = WtO + (size_t)z * 1048576;
  const u16* bi = bias + (size_t)z * 1024;
  float* C = out + (size_t)z * SIDE;

  f32x4 acc[4][4] = {};
  int srow = 32 * wave + (lane >> 2);
  int scol = (lane & 3) * 8;
  const u16* gA = A + (size_t)(m0 + srow) * 1024 + scol;
  const u16* gB = Wt + (size_t)(n0 + srow) * 1024 + scol;
  u16* lA = &As[(32 * wave) * 32];
  u16* lB = &Bs[(32 * wave) * 32];

  for (int k0 = 0; k0 < 1024; k0 += 32) {
    __syncthreads();
#pragma unroll
    for (int j = 0; j < 2; ++j) {
      __builtin_amdgcn_global_load_lds((gbl_void*)(gA + (size_t)(16 * j) * 1024 + k0),
                                       (lds_void*)(lA + 16 * j * 32), 16, 0, 0);
      __builtin_amdgcn_global_load_lds((gbl_void*)(gB + (size_t)(16 * j) * 1024 + k0),
                                       (lds_void*)(lB + 16 * j * 32), 16, 0, 0);
    }
    __syncthreads();
    bf16x8 af[4], bfr[4];
#pragma unroll
    for (int i = 0; i < 4; ++i)
      af[i] = *(const bf16x8*)&As[(64 * wr + 16 * i + lrow) * 32 + 8 * quad];
#pragma unroll
    for (int j = 0; j < 4; ++j)
      bfr[j] = *(const bf16x8*)&Bs[(64 * wc + 16 * j + lrow) * 32 + 8 * quad];
#pragma unroll
    for (int i = 0; i < 4; ++i)
#pragma unroll
      for (int j = 0; j < 4; ++j)
        acc[i][j] = __builtin_amdgcn_mfma_f32_16x16x32_bf16(af[i], bfr[j], acc[i][j], 0, 0, 0);
  }

  float bv[4];
#pragma unroll
  for (int j = 0; j < 4; ++j) bv[j] = bf2f(bi[n0 + 64 * wc + 16 * j + lrow]);
#pragma unroll
  for (int i = 0; i < 4; ++i) {
    int row = m0 + 64 * wr + 16 * i + 4 * quad;
#pragma unroll
    for (int j = 0; j < 4; ++j) {
      int col = n0 + 64 * wc + 16 * j + lrow;
#pragma unroll
      for (int r = 0; r < 4; ++r)
        C[(size_t)(row + r) * 1024 + col] = acc[i][j][r] + bv[j];
    }
  }
}

extern "C" void kernel_launch(void* const* d_in, const int* in_sizes, int n_in,
                              void* d_out, int out_size, void* d_ws, size_t ws_size,
                              hipStream_t stream) {
  (void)in_sizes; (void)n_in; (void)out_size; (void)ws_size;
  const size_t M1 = 1048576u;
  u16* ws = (u16*)d_ws;
  u16* wtA   = ws;             // [2048,1024] concat(Wa_qk^T*0.125*log2e, Wa_v^T)
  u16* wtB   = ws + 2 * M1;    // [2048,1024] concat(Wb_qk^T, Wb_v^T)
  u16* wtO   = ws + 4 * M1;    // [2048,1024] concat(Wa_o^T, Wb_o^T)
  u16* biasQ = ws + 6 * M1;    // [2,2048]
  u16* biasO = ws + 6 * M1 + 4096;  // [2,1024]
  u16* ab    = ws + 7 * M1;    // [2][4096,1024] bf16 inputs (dead after QKV)
  u16* vt    = ab;             // alias: [2][bh][64][2048]
  u16* qkbuf = ws + 15 * M1;   // [2][bh][2048][64]
  u16* vbuf  = ws + 23 * M1;   // [2][bh][2048][64] (dead after transpose_v)
  u16* ctx   = vbuf;           // alias: [2][4096,1024]

  dim3 blk(256);
  k_cvt_in<<<dim3(2048, 2), blk, 0, stream>>>((const float*)d_in[0],
                                              (const float*)d_in[1], ab);
  k_cvt_bias<<<dim3(4, 6), blk, 0, stream>>>(
      (const float*)d_in[3], (const float*)d_in[5], (const float*)d_in[7],
      (const float*)d_in[9], (const float*)d_in[11], (const float*)d_in[13], biasQ);
  k_transpose_w<<<dim3(16, 16, 6), blk, 0, stream>>>(
      (const float*)d_in[2], (const float*)d_in[4], (const float*)d_in[6],
      (const float*)d_in[8], (const float*)d_in[10], (const float*)d_in[12],
      wtA, wtA + M1, wtB, wtB + M1, wtO, wtO + M1);
  k_gemm_qkv<<<dim3(16, 32, 2), blk, 0, stream>>>(ab, wtA, wtB, biasQ, qkbuf, vbuf);
  k_transpose_v<<<dim3(32, 64), blk, 0, stream>>>(vbuf, vt);
  k_attn<<<dim3(32, 16, 2), blk, 0, stream>>>(qkbuf, vt, ctx);
  k_gemm_o<<<dim3(8, 32, 2), blk, 0, stream>>>(ctx, wtO, biasO, (float*)d_out);
}